// Round 11
// baseline (654.306 us; speedup 1.0000x reference)
//
#include <hip/hip_runtime.h>

typedef float f4 __attribute__((ext_vector_type(4)));
typedef float f2 __attribute__((ext_vector_type(2)));
typedef int   i4 __attribute__((ext_vector_type(4)));
typedef short bf16x8 __attribute__((ext_vector_type(8)));
typedef unsigned short u16x8 __attribute__((ext_vector_type(8)));
typedef unsigned short u16x4 __attribute__((ext_vector_type(4)));
typedef float f32x4 __attribute__((ext_vector_type(4)));

constexpr int HIDDEN     = 128;
constexpr int OUT_EMB    = 256;
constexpr int OUT_CH     = 128;
constexpr int NUM_RADIAL = 6;
constexpr int NBLK       = 128;  // nodes per block in MLP kernel

// weight segment offsets inside concatenated whi/wlo
constexpr int OFF_Wp = 0;                       // [256][128]
constexpr int OFF_W0 = OFF_Wp + 256 * 128;      // [256][256]
constexpr int OFF_W1 = OFF_W0 + 256 * 256;
constexpr int OFF_W2 = OFF_W1 + 256 * 256;
constexpr int OFF_Wf = OFF_W2 + 256 * 256;      // [128][256]
constexpr int WTOT   = OFF_Wf + 128 * 256;      // 262144

// ---------------- bf16 helpers (RNE) ----------------
__device__ __forceinline__ unsigned short f2bf(float f) {
    unsigned int u = __float_as_uint(f);
    return (unsigned short)((u + 0x7FFFu + ((u >> 16) & 1u)) >> 16);
}
__device__ __forceinline__ float bf2f(unsigned short h) {
    return __uint_as_float(((unsigned int)h) << 16);
}

// ---------------------------------------------------------------------------
// Prep: zero histogram + split all 5 weight matrices f32 -> bf16 hi/lo.
// ---------------------------------------------------------------------------
__global__ __launch_bounds__(256) void prep_kernel(
    const float* __restrict__ Wp, const float* __restrict__ W0,
    const float* __restrict__ W1, const float* __restrict__ W2,
    const float* __restrict__ Wf,
    unsigned short* __restrict__ whi, unsigned short* __restrict__ wlo,
    int* __restrict__ count, int N)
{
    const int i = blockIdx.x * 256 + threadIdx.x;
    if (i < N) count[i] = 0;
    if (i < WTOT) {
        const float* src; int off;
        if      (i < OFF_W0) { src = Wp; off = i - OFF_Wp; }
        else if (i < OFF_W1) { src = W0; off = i - OFF_W0; }
        else if (i < OFF_W2) { src = W1; off = i - OFF_W1; }
        else if (i < OFF_Wf) { src = W2; off = i - OFF_W2; }
        else                 { src = Wf; off = i - OFF_Wf; }
        float v = src[off];
        unsigned short h = f2bf(v);
        whi[i] = h;
        wlo[i] = f2bf(v - bf2f(h));
    }
}

// ---------------------------------------------------------------------------
// Phase 1a: histogram of edge target nodes (int4-vectorized)
// ---------------------------------------------------------------------------
__global__ __launch_bounds__(256) void hist_kernel(const int* __restrict__ idx,
                                                   int* __restrict__ count, long E)
{
    long i = ((long)blockIdx.x * blockDim.x + threadIdx.x) * 4;
    if (i + 3 < E) {
        i4 v = *(const i4*)(idx + i);
#pragma unroll
        for (int k = 0; k < 4; ++k) atomicAdd(&count[v[k]], 1);
    } else {
        for (long t = i; t < E; ++t) atomicAdd(&count[idx[t]], 1);
    }
}

// ---------------------------------------------------------------------------
// Phase 1b: coalesced 3-kernel exclusive scan over N counts.
// ---------------------------------------------------------------------------
__global__ __launch_bounds__(256) void scan_bsum_kernel(const int* __restrict__ count,
                                                        int* __restrict__ bsum, int N)
{
    __shared__ int red[4];
    const int i = blockIdx.x * 256 + threadIdx.x;
    int v = (i < N) ? count[i] : 0;
#pragma unroll
    for (int off = 1; off < 64; off <<= 1) v += __shfl_xor(v, off);
    if ((threadIdx.x & 63) == 0) red[threadIdx.x >> 6] = v;
    __syncthreads();
    if (threadIdx.x == 0) bsum[blockIdx.x] = red[0] + red[1] + red[2] + red[3];
}

__global__ __launch_bounds__(256) void scan_base_kernel(const int* __restrict__ bsum,
                                                        int* __restrict__ bbase,
                                                        int* __restrict__ start,
                                                        int nb, int N, int E)
{
    __shared__ int s[256];
    const int t = threadIdx.x;
    int v = (t < nb) ? bsum[t] : 0;
    s[t] = v;
    __syncthreads();
    for (int off = 1; off < 256; off <<= 1) {
        int a = s[t];
        int b = (t >= off) ? s[t - off] : 0;
        __syncthreads();
        s[t] = a + b;
        __syncthreads();
    }
    if (t < nb) bbase[t] = s[t] - v;       // exclusive block base
    if (t == 0) start[N] = E;
}

__global__ __launch_bounds__(256) void scan_write_kernel(const int* __restrict__ count,
                                                         const int* __restrict__ bbase,
                                                         int* __restrict__ start,
                                                         int* __restrict__ cursor, int N)
{
    __shared__ int s[256];
    const int t = threadIdx.x;
    const int i = blockIdx.x * 256 + t;
    int v = (i < N) ? count[i] : 0;
    s[t] = v;
    __syncthreads();
    for (int off = 1; off < 256; off <<= 1) {
        int a = s[t];
        int b = (t >= off) ? s[t - off] : 0;
        __syncthreads();
        s[t] = a + b;
        __syncthreads();
    }
    if (i < N) {
        int sv = bbase[blockIdx.x] + s[t] - v;  // exclusive prefix
        start[i]  = sv;
        cursor[i] = sv;
    }
}

// ---------------------------------------------------------------------------
// Phase 1c+1d fused: scatter-materialize. Half-wave (32 lanes) per edge,
// edges processed in SEQUENTIAL order (x/rbf stream at full BW). msg row
// (128 bf16 = 256B) written to its CSR slot: scattered fire-and-forget write.
// ---------------------------------------------------------------------------
__global__ __launch_bounds__(256) void scatter_mat_kernel(
    const float* __restrict__ x, const float* __restrict__ rbf,
    const float* __restrict__ Wb, const int* __restrict__ idx,
    int* __restrict__ cursor, unsigned short* __restrict__ msgC, long E)
{
    const int l    = threadIdx.x & 31;
    const int half = (threadIdx.x >> 5) & 1;
    const int hw   = threadIdx.x >> 5;           // half-wave id in block (0..7)

    float wb[4][NUM_RADIAL];
#pragma unroll
    for (int c = 0; c < 4; ++c)
#pragma unroll
        for (int r = 0; r < NUM_RADIAL; ++r)
            wb[c][r] = Wb[(4 * l + c) * NUM_RADIAL + r];

    for (long e = (long)blockIdx.x * 8 + hw; e < E; e += (long)gridDim.x * 8) {
        const int node = idx[e];
        int pos;
        if (l == 0) pos = atomicAdd(&cursor[node], 1);
        pos = __shfl(pos, half << 5);            // broadcast within half-wave

        const float* rp = rbf + e * NUM_RADIAL;
        f2 r01 = *(const f2*)(rp);
        f2 r23 = *(const f2*)(rp + 2);
        f2 r45 = *(const f2*)(rp + 4);
        f4 xv  = *(const f4*)(x + e * HIDDEN + 4 * l);
        float rr[NUM_RADIAL] = {r01[0], r01[1], r23[0], r23[1], r45[0], r45[1]};

        u16x4 o;
#pragma unroll
        for (int c = 0; c < 4; ++c) {
            float b = 0.f;
#pragma unroll
            for (int r = 0; r < NUM_RADIAL; ++r)
                b = __builtin_fmaf(rr[r], wb[c][r], b);
            o[c] = f2bf(b * xv[c]);
        }
        *(u16x4*)(msgC + (long)pos * HIDDEN + 4 * l) = o;   // 256B/edge contiguous
    }
}

// ---------------------------------------------------------------------------
// Node MLP, MFMA, with fused segment-sum prologue. Block = 128 nodes; its
// msgC segment [start[node0], start[node0+128]) is CONTIGUOUS -> pure
// streaming read. Wave w sums nodes w*16..w*16+15 (lane owns ch 2l,2l+1).
// ---------------------------------------------------------------------------
__device__ __forceinline__ int swz(int node, int col) {
    return (node * 256 + col) ^ ((node & 7) << 3);
}

template <int IN, int OUT, bool BIAS_ACT, bool LAST>
__device__ __forceinline__ void mfma_layer(
    const unsigned short* __restrict__ whi, const unsigned short* __restrict__ wlo,
    const float* __restrict__ bias,
    unsigned short* H, float* __restrict__ outp,
    int node0, int N, int wm, int wn, int lane)
{
    const int lr = lane & 15;
    const int lg = lane >> 4;
    constexpr int NT = OUT / 64;
    const int wbase = wn * (OUT / 4);
    const int mrow0 = wm * 64;

    f32x4 acc[4][NT];
#pragma unroll
    for (int nt = 0; nt < NT; ++nt) {
        float bb = 0.f;
        if constexpr (BIAS_ACT) bb = bias[wbase + nt * 16 + lr];
#pragma unroll
        for (int mt = 0; mt < 4; ++mt) {
            acc[mt][nt][0] = bb; acc[mt][nt][1] = bb;
            acc[mt][nt][2] = bb; acc[mt][nt][3] = bb;
        }
    }

    for (int ks = 0; ks < IN / 32; ++ks) {
        const int k0 = ks * 32 + lg * 8;
        bf16x8 ah[4];
#pragma unroll
        for (int mt = 0; mt < 4; ++mt)
            ah[mt] = *(const bf16x8*)&H[swz(mrow0 + mt * 16 + lr, k0)];
#pragma unroll
        for (int nt = 0; nt < NT; ++nt) {
            const long wrow = (long)(wbase + nt * 16 + lr) * IN + k0;
            bf16x8 bh = *(const bf16x8*)&whi[wrow];
            bf16x8 bl = *(const bf16x8*)&wlo[wrow];
#pragma unroll
            for (int mt = 0; mt < 4; ++mt) {
                acc[mt][nt] = __builtin_amdgcn_mfma_f32_16x16x32_bf16(ah[mt], bh, acc[mt][nt], 0, 0, 0);
                acc[mt][nt] = __builtin_amdgcn_mfma_f32_16x16x32_bf16(ah[mt], bl, acc[mt][nt], 0, 0, 0);
            }
        }
    }

    __syncthreads();

#pragma unroll
    for (int mt = 0; mt < 4; ++mt) {
#pragma unroll
        for (int nt = 0; nt < NT; ++nt) {
#pragma unroll
            for (int r = 0; r < 4; ++r) {
                float v = acc[mt][nt][r];
                if constexpr (BIAS_ACT) v = v / (1.f + __expf(-v));
                const int node = mrow0 + mt * 16 + lg * 4 + r;
                const int col  = wbase + nt * 16 + lr;
                if constexpr (LAST) {
                    if (node0 + node < N) outp[(long)(node0 + node) * OUT + col] = v;
                } else {
                    H[swz(node, col)] = f2bf(v);
                }
            }
        }
    }
    if constexpr (!LAST) __syncthreads();
}

__global__ __launch_bounds__(512, 4) void node_mlp_mfma_kernel(
    const unsigned short* __restrict__ msgC,
    const int* __restrict__ startp,
    const unsigned short* __restrict__ whi, const unsigned short* __restrict__ wlo,
    const float* __restrict__ b0, const float* __restrict__ b1,
    const float* __restrict__ b2,
    float* __restrict__ out, int N)
{
    __shared__ unsigned short H[NBLK * 256];   // 64 KB

    const int tid   = threadIdx.x;
    const int w     = tid >> 6;
    const int lane  = tid & 63;
    const int wm    = w >> 2;
    const int wn    = w & 3;
    const int node0 = blockIdx.x * NBLK;

    // ---- fused segment-sum: wave w handles nodes w*16 .. w*16+15 ----
    for (int nn = 0; nn < 16; ++nn) {
        const int lrow = w * 16 + nn;
        const int node = node0 + lrow;
        float aa[16];
#pragma unroll
        for (int k = 0; k < 16; ++k) aa[k] = 0.f;

        if (node < N) {
            const int j0 = startp[node], j1 = startp[node + 1];
            int j = j0;
            for (; j + 7 < j1; j += 8) {           // 8 rows (2KB) in flight
                unsigned int v[8];
#pragma unroll
                for (int k = 0; k < 8; ++k)
                    v[k] = *(const unsigned int*)(msgC + (long)(j + k) * HIDDEN + 2 * lane);
#pragma unroll
                for (int k = 0; k < 8; ++k) {
                    aa[2 * (k & 3)]     += bf2f((unsigned short)(v[k] & 0xffff));
                    aa[2 * (k & 3) + 1] += bf2f((unsigned short)(v[k] >> 16));
                }
            }
            for (; j < j1; ++j) {
                unsigned int v = *(const unsigned int*)(msgC + (long)j * HIDDEN + 2 * lane);
                aa[0] += bf2f((unsigned short)(v & 0xffff));
                aa[1] += bf2f((unsigned short)(v >> 16));
            }
        }
        float s0 = (aa[0] + aa[2]) + (aa[4] + aa[6]);
        float s1 = (aa[1] + aa[3]) + (aa[5] + aa[7]);
        unsigned int packed = (unsigned int)f2bf(s0) | ((unsigned int)f2bf(s1) << 16);
        *(unsigned int*)&H[swz(lrow, 2 * lane)] = packed;
    }
    __syncthreads();

    mfma_layer<HIDDEN,  OUT_EMB, false, false>(whi + OFF_Wp, wlo + OFF_Wp, nullptr, H, nullptr, node0, N, wm, wn, lane);
    mfma_layer<OUT_EMB, OUT_EMB, true,  false>(whi + OFF_W0, wlo + OFF_W0, b0,      H, nullptr, node0, N, wm, wn, lane);
    mfma_layer<OUT_EMB, OUT_EMB, true,  false>(whi + OFF_W1, wlo + OFF_W1, b1,      H, nullptr, node0, N, wm, wn, lane);
    mfma_layer<OUT_EMB, OUT_EMB, true,  false>(whi + OFF_W2, wlo + OFF_W2, b2,      H, nullptr, node0, N, wm, wn, lane);
    mfma_layer<OUT_EMB, OUT_CH,  false, true >(whi + OFF_Wf, wlo + OFF_Wf, nullptr, H, out,     node0, N, wm, wn, lane);
}

// ---------------------------------------------------------------------------
extern "C" void kernel_launch(void* const* d_in, const int* in_sizes, int n_in,
                              void* d_out, int out_size, void* d_ws, size_t ws_size,
                              hipStream_t stream)
{
    const float* x   = (const float*)d_in[0];
    const float* rbf = (const float*)d_in[1];
    const int*   idx = (const int*)d_in[2];
    const float* Wb  = (const float*)d_in[4];
    const float* Wp  = (const float*)d_in[5];
    const float* Wf  = (const float*)d_in[6];
    const float* W0  = (const float*)d_in[7];
    const float* b0  = (const float*)d_in[8];
    const float* W1  = (const float*)d_in[9];
    const float* b1  = (const float*)d_in[10];
    const float* W2  = (const float*)d_in[11];
    const float* b2  = (const float*)d_in[12];

    const long E = (long)in_sizes[0] / HIDDEN;
    const int  N = out_size / OUT_CH;
    const int  nb = (N + 255) / 256;

    // workspace layout (ws ~3.2 GB per harness poison size; we use ~412 MB)
    int* count  = (int*)d_ws;                            // N
    int* startp = count + N;                             // N+1
    int* cursor = startp + N + 1;                        // N
    int* bsum   = cursor + N;                            // nb
    int* bbase  = bsum + nb;                             // nb
    uintptr_t p = (uintptr_t)(bbase + nb);
    p = (p + 255) & ~(uintptr_t)255;
    unsigned short* msgC = (unsigned short*)p;           // E*HIDDEN bf16 (410MB)
    unsigned short* whi  = msgC + (long)E * HIDDEN;      // WTOT
    unsigned short* wlo  = whi + WTOT;                   // WTOT

    const int pb = (max((int)WTOT, N) + 255) / 256;
    prep_kernel<<<pb, 256, 0, stream>>>(Wp, W0, W1, W2, Wf, whi, wlo, count, N);

    const long Eq = (E + 3) / 4;
    const int eb = (int)((Eq + 255) / 256);
    hist_kernel<<<eb, 256, 0, stream>>>(idx, count, E);

    scan_bsum_kernel<<<nb, 256, 0, stream>>>(count, bsum, N);
    scan_base_kernel<<<1, 256, 0, stream>>>(bsum, bbase, startp, nb, N, (int)E);
    scan_write_kernel<<<nb, 256, 0, stream>>>(count, bbase, startp, cursor, N);

    scatter_mat_kernel<<<8192, 256, 0, stream>>>(x, rbf, Wb, idx, cursor, msgC, E);

    node_mlp_mfma_kernel<<<(N + NBLK - 1) / NBLK, 512, 0, stream>>>(
        msgC, startp, whi, wlo, b0, b1, b2, (float*)d_out, N);
}

// Round 12
// 600.505 us; speedup vs baseline: 1.0896x; 1.0896x over previous
//
#include <hip/hip_runtime.h>

typedef float f4 __attribute__((ext_vector_type(4)));
typedef float f2 __attribute__((ext_vector_type(2)));
typedef int   i4 __attribute__((ext_vector_type(4)));
typedef short bf16x8 __attribute__((ext_vector_type(8)));
typedef unsigned short u16x8 __attribute__((ext_vector_type(8)));
typedef unsigned short u16x4 __attribute__((ext_vector_type(4)));
typedef float f32x4 __attribute__((ext_vector_type(4)));

constexpr int HIDDEN     = 128;
constexpr int OUT_EMB    = 256;
constexpr int OUT_CH     = 128;
constexpr int NUM_RADIAL = 6;
constexpr int NBLK       = 128;  // nodes per block in MLP kernel

// weight segment offsets inside concatenated whi/wlo
constexpr int OFF_Wp = 0;                       // [256][128]
constexpr int OFF_W0 = OFF_Wp + 256 * 128;      // [256][256]
constexpr int OFF_W1 = OFF_W0 + 256 * 256;
constexpr int OFF_W2 = OFF_W1 + 256 * 256;
constexpr int OFF_Wf = OFF_W2 + 256 * 256;      // [128][256]
constexpr int WTOT   = OFF_Wf + 128 * 256;      // 262144

// ---------------- bf16 helpers (RNE) ----------------
__device__ __forceinline__ unsigned short f2bf(float f) {
    unsigned int u = __float_as_uint(f);
    return (unsigned short)((u + 0x7FFFu + ((u >> 16) & 1u)) >> 16);
}
__device__ __forceinline__ float bf2f(unsigned short h) {
    return __uint_as_float(((unsigned int)h) << 16);
}

// ---------------------------------------------------------------------------
// Prep: zero histogram + split all 5 weight matrices f32 -> bf16 hi/lo.
// ---------------------------------------------------------------------------
__global__ __launch_bounds__(256) void prep_kernel(
    const float* __restrict__ Wp, const float* __restrict__ W0,
    const float* __restrict__ W1, const float* __restrict__ W2,
    const float* __restrict__ Wf,
    unsigned short* __restrict__ whi, unsigned short* __restrict__ wlo,
    int* __restrict__ count, int N)
{
    const int i = blockIdx.x * 256 + threadIdx.x;
    if (i < N) count[i] = 0;
    if (i < WTOT) {
        const float* src; int off;
        if      (i < OFF_W0) { src = Wp; off = i - OFF_Wp; }
        else if (i < OFF_W1) { src = W0; off = i - OFF_W0; }
        else if (i < OFF_W2) { src = W1; off = i - OFF_W1; }
        else if (i < OFF_Wf) { src = W2; off = i - OFF_W2; }
        else                 { src = Wf; off = i - OFF_Wf; }
        float v = src[off];
        unsigned short h = f2bf(v);
        whi[i] = h;
        wlo[i] = f2bf(v - bf2f(h));
    }
}

// ---------------------------------------------------------------------------
// Phase 1a: histogram of edge target nodes (int4-vectorized)
// ---------------------------------------------------------------------------
__global__ __launch_bounds__(256) void hist_kernel(const int* __restrict__ idx,
                                                   int* __restrict__ count, long E)
{
    long i = ((long)blockIdx.x * blockDim.x + threadIdx.x) * 4;
    if (i + 3 < E) {
        i4 v = *(const i4*)(idx + i);
#pragma unroll
        for (int k = 0; k < 4; ++k) atomicAdd(&count[v[k]], 1);
    } else {
        for (long t = i; t < E; ++t) atomicAdd(&count[idx[t]], 1);
    }
}

// ---------------------------------------------------------------------------
// Phase 1b: coalesced 3-kernel exclusive scan over N counts.
// ---------------------------------------------------------------------------
__global__ __launch_bounds__(256) void scan_bsum_kernel(const int* __restrict__ count,
                                                        int* __restrict__ bsum, int N)
{
    __shared__ int red[4];
    const int i = blockIdx.x * 256 + threadIdx.x;
    int v = (i < N) ? count[i] : 0;
#pragma unroll
    for (int off = 1; off < 64; off <<= 1) v += __shfl_xor(v, off);
    if ((threadIdx.x & 63) == 0) red[threadIdx.x >> 6] = v;
    __syncthreads();
    if (threadIdx.x == 0) bsum[blockIdx.x] = red[0] + red[1] + red[2] + red[3];
}

__global__ __launch_bounds__(256) void scan_base_kernel(const int* __restrict__ bsum,
                                                        int* __restrict__ bbase,
                                                        int* __restrict__ start,
                                                        int nb, int N, int E)
{
    __shared__ int s[256];
    const int t = threadIdx.x;
    int v = (t < nb) ? bsum[t] : 0;
    s[t] = v;
    __syncthreads();
    for (int off = 1; off < 256; off <<= 1) {
        int a = s[t];
        int b = (t >= off) ? s[t - off] : 0;
        __syncthreads();
        s[t] = a + b;
        __syncthreads();
    }
    if (t < nb) bbase[t] = s[t] - v;       // exclusive block base
    if (t == 0) start[N] = E;
}

__global__ __launch_bounds__(256) void scan_write_kernel(const int* __restrict__ count,
                                                         const int* __restrict__ bbase,
                                                         int* __restrict__ start,
                                                         int* __restrict__ cursor, int N)
{
    __shared__ int s[256];
    const int t = threadIdx.x;
    const int i = blockIdx.x * 256 + t;
    int v = (i < N) ? count[i] : 0;
    s[t] = v;
    __syncthreads();
    for (int off = 1; off < 256; off <<= 1) {
        int a = s[t];
        int b = (t >= off) ? s[t - off] : 0;
        __syncthreads();
        s[t] = a + b;
        __syncthreads();
    }
    if (i < N) {
        int sv = bbase[blockIdx.x] + s[t] - v;  // exclusive prefix
        start[i]  = sv;
        cursor[i] = sv;
    }
}

// ---------------------------------------------------------------------------
// Phase 1c: scatter edge ids into CSR order AND materialize rbf in CSR order.
// rbf is read SEQUENTIALLY here (streaming); rbfC written scattered (24B,
// fire-and-forget). This removes the per-edge random rbf transaction from
// the gather's critical random-read stream.
// ---------------------------------------------------------------------------
__global__ __launch_bounds__(256) void scatter_perm_kernel(const int* __restrict__ idx,
                                                           const float* __restrict__ rbf,
                                                           int* __restrict__ cursor,
                                                           int* __restrict__ perm,
                                                           float* __restrict__ rbfC, long E)
{
    long i = ((long)blockIdx.x * blockDim.x + threadIdx.x) * 4;
    if (i + 3 < E) {
        i4 v = *(const i4*)(idx + i);
#pragma unroll
        for (int k = 0; k < 4; ++k) {
            int p = atomicAdd(&cursor[v[k]], 1);
            perm[p] = (int)(i + k);
            const float* rp = rbf + (i + k) * NUM_RADIAL;
            float* wp = rbfC + (long)p * NUM_RADIAL;
            *(f2*)(wp)     = *(const f2*)(rp);
            *(f2*)(wp + 2) = *(const f2*)(rp + 2);
            *(f2*)(wp + 4) = *(const f2*)(rp + 4);
        }
    } else {
        for (long t = i; t < E; ++t) {
            int p = atomicAdd(&cursor[idx[t]], 1);
            perm[p] = (int)t;
            const float* rp = rbf + t * NUM_RADIAL;
            float* wp = rbfC + (long)p * NUM_RADIAL;
            *(f2*)(wp)     = *(const f2*)(rp);
            *(f2*)(wp + 2) = *(const f2*)(rp + 2);
            *(f2*)(wp + 4) = *(const f2*)(rp + 4);
        }
    }
}

// ---------------------------------------------------------------------------
// Phase 1d: gather-reduce (r9 structure exactly; only rbf -> rbfC change).
// Grid-stride waves; half-wave owns stride-2 edge stream; unroll-4 per half.
// Random HBM traffic is now ONLY the x rows (pure 512B granules); perm and
// rbfC are sequential streams.
// ---------------------------------------------------------------------------
__device__ __forceinline__ void edge_accum(const float* __restrict__ x,
                                           const float* __restrict__ rrow,
                                           const float wb[4][NUM_RADIAL],
                                           int e, int l, f4& acc)
{
    f2 r01 = *(const f2*)(rrow);
    f2 r23 = *(const f2*)(rrow + 2);
    f2 r45 = *(const f2*)(rrow + 4);
    f4 xv  = *(const f4*)(x + (long)e * HIDDEN + 4 * l);
    float rb[NUM_RADIAL] = {r01[0], r01[1], r23[0], r23[1], r45[0], r45[1]};
#pragma unroll
    for (int c = 0; c < 4; ++c) {
        float b = 0.f;
#pragma unroll
        for (int r = 0; r < NUM_RADIAL; ++r) b = __builtin_fmaf(rb[r], wb[c][r], b);
        acc[c] = __builtin_fmaf(b, xv[c], acc[c]);
    }
}

__global__ __launch_bounds__(256, 6) void gather_kernel(
    const float* __restrict__ x, const float* __restrict__ rbfC,
    const float* __restrict__ Wb, const int* __restrict__ perm,
    const int* __restrict__ start, unsigned short* __restrict__ aggb,
    int N, int nwaves)
{
    const int lane = threadIdx.x & 63;
    const int half = lane >> 5;
    const int l    = lane & 31;
    const int wgid = blockIdx.x * (blockDim.x >> 6) + (threadIdx.x >> 6);

    float wb[4][NUM_RADIAL];
#pragma unroll
    for (int c = 0; c < 4; ++c)
#pragma unroll
        for (int r = 0; r < NUM_RADIAL; ++r)
            wb[c][r] = Wb[(4 * l + c) * NUM_RADIAL + r];

    for (int node = wgid; node < N; node += nwaves) {
        const int j0 = start[node], j1 = start[node + 1];
        f4 acc = {0.f, 0.f, 0.f, 0.f};

        int j = j0 + half;
        for (; j + 6 < j1; j += 8) {
            const int e0 = perm[j];
            const int e1 = perm[j + 2];
            const int e2 = perm[j + 4];
            const int e3 = perm[j + 6];
            edge_accum(x, rbfC + (long)j * NUM_RADIAL,       wb, e0, l, acc);
            edge_accum(x, rbfC + (long)(j + 2) * NUM_RADIAL, wb, e1, l, acc);
            edge_accum(x, rbfC + (long)(j + 4) * NUM_RADIAL, wb, e2, l, acc);
            edge_accum(x, rbfC + (long)(j + 6) * NUM_RADIAL, wb, e3, l, acc);
        }
        for (; j < j1; j += 2)
            edge_accum(x, rbfC + (long)j * NUM_RADIAL, wb, perm[j], l, acc);

#pragma unroll
        for (int c = 0; c < 4; ++c) acc[c] += __shfl_xor(acc[c], 32);

        if (half == 0) {
            u16x4 o;
#pragma unroll
            for (int c = 0; c < 4; ++c) o[c] = f2bf(acc[c]);
            *(u16x4*)(aggb + (long)node * HIDDEN + 4 * l) = o;
        }
    }
}

// ---------------------------------------------------------------------------
// Node MLP, MFMA (identical to round 7/9; measured ~63 us).
// ---------------------------------------------------------------------------
__device__ __forceinline__ int swz(int node, int col) {
    return (node * 256 + col) ^ ((node & 7) << 3);
}

template <int IN, int OUT, bool BIAS_ACT, bool LAST>
__device__ __forceinline__ void mfma_layer(
    const unsigned short* __restrict__ whi, const unsigned short* __restrict__ wlo,
    const float* __restrict__ bias,
    unsigned short* H, float* __restrict__ outp,
    int node0, int N, int wm, int wn, int lane)
{
    const int lr = lane & 15;
    const int lg = lane >> 4;
    constexpr int NT = OUT / 64;
    const int wbase = wn * (OUT / 4);
    const int mrow0 = wm * 64;

    f32x4 acc[4][NT];
#pragma unroll
    for (int nt = 0; nt < NT; ++nt) {
        float bb = 0.f;
        if constexpr (BIAS_ACT) bb = bias[wbase + nt * 16 + lr];
#pragma unroll
        for (int mt = 0; mt < 4; ++mt) {
            acc[mt][nt][0] = bb; acc[mt][nt][1] = bb;
            acc[mt][nt][2] = bb; acc[mt][nt][3] = bb;
        }
    }

    for (int ks = 0; ks < IN / 32; ++ks) {
        const int k0 = ks * 32 + lg * 8;
        bf16x8 ah[4];
#pragma unroll
        for (int mt = 0; mt < 4; ++mt)
            ah[mt] = *(const bf16x8*)&H[swz(mrow0 + mt * 16 + lr, k0)];
#pragma unroll
        for (int nt = 0; nt < NT; ++nt) {
            const long wrow = (long)(wbase + nt * 16 + lr) * IN + k0;
            bf16x8 bh = *(const bf16x8*)&whi[wrow];
            bf16x8 bl = *(const bf16x8*)&wlo[wrow];
#pragma unroll
            for (int mt = 0; mt < 4; ++mt) {
                acc[mt][nt] = __builtin_amdgcn_mfma_f32_16x16x32_bf16(ah[mt], bh, acc[mt][nt], 0, 0, 0);
                acc[mt][nt] = __builtin_amdgcn_mfma_f32_16x16x32_bf16(ah[mt], bl, acc[mt][nt], 0, 0, 0);
            }
        }
    }

    __syncthreads();

#pragma unroll
    for (int mt = 0; mt < 4; ++mt) {
#pragma unroll
        for (int nt = 0; nt < NT; ++nt) {
#pragma unroll
            for (int r = 0; r < 4; ++r) {
                float v = acc[mt][nt][r];
                if constexpr (BIAS_ACT) v = v / (1.f + __expf(-v));
                const int node = mrow0 + mt * 16 + lg * 4 + r;
                const int col  = wbase + nt * 16 + lr;
                if constexpr (LAST) {
                    if (node0 + node < N) outp[(long)(node0 + node) * OUT + col] = v;
                } else {
                    H[swz(node, col)] = f2bf(v);
                }
            }
        }
    }
    if constexpr (!LAST) __syncthreads();
}

__global__ __launch_bounds__(512, 4) void node_mlp_mfma_kernel(
    const unsigned short* __restrict__ aggb,
    const unsigned short* __restrict__ whi, const unsigned short* __restrict__ wlo,
    const float* __restrict__ b0, const float* __restrict__ b1,
    const float* __restrict__ b2,
    float* __restrict__ out, int N)
{
    __shared__ unsigned short H[NBLK * 256];   // 64 KB

    const int tid   = threadIdx.x;
    const int w     = tid >> 6;
    const int lane  = tid & 63;
    const int wm    = w >> 2;
    const int wn    = w & 3;
    const int node0 = blockIdx.x * NBLK;

#pragma unroll
    for (int i = 0; i < (NBLK * HIDDEN) / (512 * 8); ++i) {
        const int e    = (i * 512 + tid) * 8;
        const int node = e >> 7;
        const int col  = e & 127;
        u16x8 v = {0, 0, 0, 0, 0, 0, 0, 0};
        if (node0 + node < N) v = *(const u16x8*)(aggb + (long)(node0 + node) * HIDDEN + col);
        *(u16x8*)&H[swz(node, col)] = v;
    }
    __syncthreads();

    mfma_layer<HIDDEN,  OUT_EMB, false, false>(whi + OFF_Wp, wlo + OFF_Wp, nullptr, H, nullptr, node0, N, wm, wn, lane);
    mfma_layer<OUT_EMB, OUT_EMB, true,  false>(whi + OFF_W0, wlo + OFF_W0, b0,      H, nullptr, node0, N, wm, wn, lane);
    mfma_layer<OUT_EMB, OUT_EMB, true,  false>(whi + OFF_W1, wlo + OFF_W1, b1,      H, nullptr, node0, N, wm, wn, lane);
    mfma_layer<OUT_EMB, OUT_EMB, true,  false>(whi + OFF_W2, wlo + OFF_W2, b2,      H, nullptr, node0, N, wm, wn, lane);
    mfma_layer<OUT_EMB, OUT_CH,  false, true >(whi + OFF_Wf, wlo + OFF_Wf, nullptr, H, out,     node0, N, wm, wn, lane);
}

// ---------------------------------------------------------------------------
extern "C" void kernel_launch(void* const* d_in, const int* in_sizes, int n_in,
                              void* d_out, int out_size, void* d_ws, size_t ws_size,
                              hipStream_t stream)
{
    const float* x   = (const float*)d_in[0];
    const float* rbf = (const float*)d_in[1];
    const int*   idx = (const int*)d_in[2];
    const float* Wb  = (const float*)d_in[4];
    const float* Wp  = (const float*)d_in[5];
    const float* Wf  = (const float*)d_in[6];
    const float* W0  = (const float*)d_in[7];
    const float* b0  = (const float*)d_in[8];
    const float* W1  = (const float*)d_in[9];
    const float* b1  = (const float*)d_in[10];
    const float* W2  = (const float*)d_in[11];
    const float* b2  = (const float*)d_in[12];

    const long E = (long)in_sizes[0] / HIDDEN;
    const int  N = out_size / OUT_CH;
    const int  nb = (N + 255) / 256;

    // workspace layout
    unsigned short* aggb = (unsigned short*)d_ws;        // N*HIDDEN bf16
    int* count  = (int*)(aggb + (long)N * HIDDEN);       // N
    int* startp = count + N;                             // N+1
    int* cursor = startp + N + 1;                        // N
    int* bsum   = cursor + N;                            // nb
    int* bbase  = bsum + nb;                             // nb
    int* perm   = bbase + nb;                            // E
    uintptr_t p = (uintptr_t)(perm + E);
    p = (p + 255) & ~(uintptr_t)255;
    float* rbfC = (float*)p;                             // E*6 f32 (38.4MB)
    unsigned short* whi = (unsigned short*)(rbfC + (long)E * NUM_RADIAL);  // WTOT
    unsigned short* wlo = whi + WTOT;                    // WTOT

    const int pb = (max((int)WTOT, N) + 255) / 256;
    prep_kernel<<<pb, 256, 0, stream>>>(Wp, W0, W1, W2, Wf, whi, wlo, count, N);

    const long Eq = (E + 3) / 4;
    const int eb = (int)((Eq + 255) / 256);
    hist_kernel<<<eb, 256, 0, stream>>>(idx, count, E);

    scan_bsum_kernel<<<nb, 256, 0, stream>>>(count, bsum, N);
    scan_base_kernel<<<1, 256, 0, stream>>>(bsum, bbase, startp, nb, N, (int)E);
    scan_write_kernel<<<nb, 256, 0, stream>>>(count, bbase, startp, cursor, N);

    scatter_perm_kernel<<<eb, 256, 0, stream>>>(idx, rbf, cursor, perm, rbfC, E);

    const int gblocks = 2048;
    const int nwaves  = gblocks * 4;
    gather_kernel<<<gblocks, 256, 0, stream>>>(x, rbfC, Wb, perm, startp, aggb, N, nwaves);

    node_mlp_mfma_kernel<<<(N + NBLK - 1) / NBLK, 512, 0, stream>>>(
        aggb, whi, wlo, b0, b1, b2, (float*)d_out, N);
}